// Round 9
// baseline (444.245 us; speedup 1.0000x reference)
//
#include <hip/hip_runtime.h>
#include <cstdint>
#include <cstddef>

typedef unsigned short u16x8 __attribute__((ext_vector_type(8)));
typedef unsigned short u16x4 __attribute__((ext_vector_type(4)));
typedef __bf16 bf16x8 __attribute__((ext_vector_type(8)));
typedef float f32x4 __attribute__((ext_vector_type(4)));

__device__ __forceinline__ float b2f(unsigned short u) {
    union { unsigned int i; float f; } v;
    v.i = ((unsigned int)u) << 16;
    return v.f;
}

__device__ __forceinline__ unsigned short f2b(float f) {
    union { float f; unsigned int i; } v;
    v.f = f;
    unsigned int x = v.i;
    unsigned int lsb = (x >> 16) & 1u;
    x += 0x7FFFu + lsb;           // round-to-nearest-even
    return (unsigned short)(x >> 16);
}

__device__ __forceinline__ float gelu_exact(float x) {
    return 0.5f * x * (1.0f + erff(x * 0.70710678118654752f));
}

// async 16B global -> LDS (DMA). lds base is wave-uniform; lane i lands at
// base + i*16 bytes. [m97: global_load_lds_dwordx4]
__device__ __forceinline__ void ld_lds16(const unsigned short* g, unsigned short* l) {
    __builtin_amdgcn_global_load_lds(
        (const __attribute__((address_space(1))) void*)g,
        (__attribute__((address_space(3))) void*)l, 16, 0, 0);
}

// ---------------------------------------------------------------------------
// Device bodies for the fused block-range kernels.
// ---------------------------------------------------------------------------

// Transpose + cast (+ optional per-input-row scale): in R x C fp32 ->
// out[c*ldout + r] = in[r][c] * scale[r]. One 32x32 tile per block.
__device__ __forceinline__ void transp_body(const float* __restrict__ in,
                                            unsigned short* __restrict__ out,
                                            int R, int C, int ldout,
                                            const float* __restrict__ scale,
                                            int bx, int by) {
    __shared__ float tile[32][33];
    const int tx = threadIdx.x & 31;
    const int ty = threadIdx.x >> 5;     // 0..7
    int x = bx * 32 + tx;
    int y0 = by * 32;
    for (int k = 0; k < 32; k += 8)
        tile[ty + k][tx] = in[(size_t)(y0 + ty + k) * C + x];
    __syncthreads();
    int ox = y0 + tx;                    // input row index
    int oy = bx * 32;
    float sc = scale ? scale[ox] : 1.0f;
    for (int k = 0; k < 32; k += 8)
        out[(size_t)(oy + ty + k) * ldout + ox] = f2b(tile[tx][ty + k] * sc);
}

// K-parallel partial of c0/c1 (16 k-chunks x 4 n-chunks, no atomics).
__device__ __forceinline__ void c01_partial_body(const float* __restrict__ W2,
                                                 const float* __restrict__ g,
                                                 const float* __restrict__ b,
                                                 float* __restrict__ pc0,
                                                 float* __restrict__ pc1,
                                                 int N, int kc, int nb) {
    int n = (nb << 8) + threadIdx.x;
    int k0 = kc << 8;
    float p0 = 0.f, p1 = 0.f;
    for (int k = k0; k < k0 + 256; ++k) {
        float w = W2[(size_t)k * N + n];
        p0 += b[k] * w;
        p1 += g[k] * w;
    }
    pc0[kc * 1024 + n] = p0;
    pc1[kc * 1024 + n] = p1;
}

// LayerNorm over 1024 fp32 cols -> bf16, fully vectorized. One row per block.
__device__ __forceinline__ void ln1024_body(const float* __restrict__ in,
                                            unsigned short* __restrict__ out,
                                            const float* __restrict__ g,
                                            const float* __restrict__ b,
                                            int row) {
    const int t = threadIdx.x;
    f32x4 v = ((const f32x4*)(in + (size_t)row * 1024))[t];
    float s = v[0] + v[1] + v[2] + v[3];
    float s2 = v[0] * v[0] + v[1] * v[1] + v[2] * v[2] + v[3] * v[3];
#pragma unroll
    for (int o = 32; o > 0; o >>= 1) {
        s  += __shfl_down(s, o, 64);
        s2 += __shfl_down(s2, o, 64);
    }
    __shared__ float red[8];
    int lane = t & 63, w = t >> 6;
    if (lane == 0) { red[w] = s; red[4 + w] = s2; }
    __syncthreads();
    if (t == 0) {
        red[0] = red[0] + red[1] + red[2] + red[3];
        red[4] = red[4] + red[5] + red[6] + red[7];
    }
    __syncthreads();
    const float inv_n = 1.0f / 1024.0f;
    float mu = red[0] * inv_n;
    float var = red[4] * inv_n - mu * mu;
    float rs = rsqrtf(var + 1e-5f);
    f32x4 gv = ((const f32x4*)g)[t];
    f32x4 bv = ((const f32x4*)b)[t];
    u16x4 ov;
#pragma unroll
    for (int r = 0; r < 4; ++r) ov[r] = f2b((v[r] - mu) * rs * gv[r] + bv[r]);
    ((u16x4*)(out + (size_t)row * 1024))[t] = ov;
}

// ---------------------------------------------------------------------------
// 128x128x32 GEMM body (2-phase, double-buffered gload_lds, XOR swizzle,
// XCD-aware bijective flat-id swizzle). A,BT bf16; fp32 acc; 256 threads.
// EPI 0: bias + exact GELU -> bf16 Cb, PLUS per-(row, 64-col half) partial
//        sum/sumsq of the fp32 gelu values -> ps/pq (no atomics: each pair
//        written by exactly one lane of one block).
// EPI 3: masked adapter-up: Cb = active ? gelu(acc+bias) : 0, where
//        active = (col<256 ? idx[row]==0 : idx[row]==1). N=768.
// EPI 4: merged adapter-down: Cb = acc + bias_sel[idx[row]][col]
//        (bias table = [a256_b2 ; a512_b2], 2x1024). Writes all rows.
// EPI 2: folded-LN epilogue:
//        Cf = (rs*acc + c0b2[col] - rsmu*c1[col]) * wm + adaptive_sel*(1-wm)
// ---------------------------------------------------------------------------
template <int EPI>
__device__ __forceinline__ void gemm_body(
    unsigned short (*As)[128 * 32], unsigned short (*Bs)[128 * 32],
    int fid, int nbx, int nby,
    const unsigned short* __restrict__ A, int lda,
    const unsigned short* __restrict__ BT, int ldb,
    const float* __restrict__ bias, unsigned short* __restrict__ Cb,
    float* __restrict__ Cf, int N, int K,
    const int* __restrict__ idx,
    const float* __restrict__ wm,
    const unsigned short* __restrict__ adaptive,
    const unsigned short* __restrict__ xn,
    const float* __restrict__ c1v,
    const float* __restrict__ rstat,
    float* __restrict__ ps, float* __restrict__ pq) {
    const int t = threadIdx.x;

    int id = fid;
    const int nwg = nbx * nby;
    if ((nwg & 7) == 0) {
        const int cpx = nwg >> 3;
        id = (id & 7) * cpx + (id >> 3);
    }
    const int bx = id % nbx;
    const int by = id / nbx;
    const int m0 = by * 128;
    const int n0 = bx * 128;

    const int lane = t & 63;
    const int wid = t >> 6;

    const int srow = lane >> 2;
    const int sch  = (lane & 3) ^ (srow & 3);
    const int scol = sch << 3;

    const int wr = (wid >> 1) << 6;
    const int wc = (wid & 1) << 6;
    const int ml = lane & 15;
    const int q = lane >> 4;
    const int qsw = ((q ^ (ml & 3)) << 3);

    f32x4 acc[4][4];
#pragma unroll
    for (int i = 0; i < 4; ++i)
#pragma unroll
        for (int j = 0; j < 4; ++j)
#pragma unroll
            for (int r = 0; r < 4; ++r) acc[i][j][r] = 0.0f;

    const int nk = K >> 5;

#define STAGE(KT, BUF)                                                          \
    {                                                                           \
        _Pragma("unroll")                                                       \
        for (int hh = 0; hh < 2; ++hh) {                                        \
            int rbase = wid * 32 + hh * 16;                                     \
            int row = rbase + srow;                                             \
            ld_lds16(A  + (size_t)(m0 + row) * lda + (KT) * 32 + scol,          \
                     &As[BUF][rbase * 32]);                                     \
            ld_lds16(BT + (size_t)(n0 + row) * ldb + (KT) * 32 + scol,          \
                     &Bs[BUF][rbase * 32]);                                     \
        }                                                                       \
    }

    STAGE(0, 0);
    for (int kt = 0; kt < nk; ++kt) {
        const int cur = kt & 1;
        __syncthreads();
        if (kt + 1 < nk) STAGE(kt + 1, cur ^ 1);

        bf16x8 af[4], bf[4];
#pragma unroll
        for (int i = 0; i < 4; ++i)
            af[i] = *(const bf16x8*)(&As[cur][(wr + i * 16 + ml) * 32 + qsw]);
#pragma unroll
        for (int j = 0; j < 4; ++j)
            bf[j] = *(const bf16x8*)(&Bs[cur][(wc + j * 16 + ml) * 32 + qsw]);
#pragma unroll
        for (int i = 0; i < 4; ++i)
#pragma unroll
            for (int j = 0; j < 4; ++j)
                acc[i][j] = __builtin_amdgcn_mfma_f32_16x16x32_bf16(af[i], bf[j], acc[i][j], 0, 0, 0);
    }
#undef STAGE

    // C/D layout: col = lane&15, row = quad*4 + reg  [m89/m91-verified]
#pragma unroll
    for (int i = 0; i < 4; ++i) {
        float rsv[4], rmv[4], wv[4];
        int idv[4];
        float rsum[4], rqs[4];
        if (EPI == 0) {
#pragma unroll
            for (int r = 0; r < 4; ++r) { rsum[r] = 0.f; rqs[r] = 0.f; }
        }
        if (EPI != 0) {
#pragma unroll
            for (int r = 0; r < 4; ++r) {
                int row = m0 + wr + i * 16 + q * 4 + r;
                idv[r] = idx[row];
                if (EPI == 2) {
                    wv[r] = wm[row];
                    rsv[r] = rstat[2 * (size_t)row];
                    rmv[r] = rstat[2 * (size_t)row + 1];
                }
            }
        }
#pragma unroll
        for (int j = 0; j < 4; ++j) {
            int col = n0 + wc + j * 16 + ml;
            float bv = bias[col];
            float bv1 = (EPI == 4) ? bias[1024 + col] : 0.0f;
            float c1c = (EPI == 2) ? c1v[col] : 0.0f;
#pragma unroll
            for (int r = 0; r < 4; ++r) {
                int row = m0 + wr + i * 16 + q * 4 + r;
                size_t off = (size_t)row * N + col;
                if (EPI == 0) {
                    float g = gelu_exact(acc[i][j][r] + bv);
                    Cb[off] = f2b(g);
                    rsum[r] += g;
                    rqs[r] += g * g;
                } else if (EPI == 3) {
                    bool act = (col < 256) ? (idv[r] == 0) : (idv[r] == 1);
                    Cb[off] = f2b(act ? gelu_exact(acc[i][j][r] + bv) : 0.0f);
                } else if (EPI == 4) {
                    float bsel = (idv[r] == 1) ? bv1 : bv;
                    Cb[off] = f2b(acc[i][j][r] + bsel);
                } else {
                    float bval = rsv[r] * acc[i][j][r] + bv - rmv[r] * c1c;
                    float a = b2f((idv[r] <= 1) ? adaptive[off] : xn[off]);
                    Cf[off] = bval * wv[r] + a * (1.0f - wv[r]);
                }
            }
        }
        if (EPI == 0) {
            // reduce the 16 cols of this wave-half via q-group shfl (stays in
            // the 16-lane group since xor<=8 preserves lane>>4), then one
            // store per (row, 64-col half): ps[row*64 + (n0+wc)/64].
#pragma unroll
            for (int r = 0; r < 4; ++r) {
                float s = rsum[r], s2 = rqs[r];
                s  += __shfl_xor(s, 1);  s2 += __shfl_xor(s2, 1);
                s  += __shfl_xor(s, 2);  s2 += __shfl_xor(s2, 2);
                s  += __shfl_xor(s, 4);  s2 += __shfl_xor(s2, 4);
                s  += __shfl_xor(s, 8);  s2 += __shfl_xor(s2, 8);
                if (ml == 0) {
                    int row = m0 + wr + i * 16 + q * 4 + r;
                    size_t pidx = (size_t)row * 64 + ((n0 + wc) >> 6);
                    ps[pidx] = s;
                    pq[pidx] = s2;
                }
            }
        }
    }
}

// ---------------------------------------------------------------------------
// Kernel 1: mega_prep — all weight prep + input LN, block-range dispatched.
// [0,4096) W1T | [4096,8192) W2T*g | [8192,8448) a256w1T->awup |
// [8448,8960) a512w1T->awup+256K | [8960,9216) a256w2T->awdT (ld 768) |
// [9216,9728) a512w2T->awdT+256 (ld 768) | [9728,9731) ab1 concat |
// [9731,9739) b2sel table | [9739,9803) c01 partials | [9803,+8192) ln1024.
// ---------------------------------------------------------------------------
__global__ __launch_bounds__(256) void mega_prep(
    const float* __restrict__ W1, const float* __restrict__ W2,
    const float* __restrict__ ln_h_g, const float* __restrict__ ln_h_b,
    const float* __restrict__ a256_w1, const float* __restrict__ a512_w1,
    const float* __restrict__ a256_w2, const float* __restrict__ a512_w2,
    const float* __restrict__ a256_b1, const float* __restrict__ a512_b1,
    const float* __restrict__ a256_b2, const float* __restrict__ a512_b2,
    const float* __restrict__ x, const float* __restrict__ ln_in_g,
    const float* __restrict__ ln_in_b,
    unsigned short* __restrict__ W1T, unsigned short* __restrict__ W2T,
    unsigned short* __restrict__ awup, unsigned short* __restrict__ awdT,
    float* __restrict__ ab1, float* __restrict__ b2sel,
    float* __restrict__ pc0, float* __restrict__ pc1,
    unsigned short* __restrict__ xn) {
    const int H = 1024, F = 4096;
    int bid = blockIdx.x;
    if (bid < 4096) {
        transp_body(W1, W1T, H, F, H, nullptr, bid & 127, bid >> 7);
    } else if (bid < 8192) {
        int l = bid - 4096;
        transp_body(W2, W2T, F, H, F, ln_h_g, l & 31, l >> 5);
    } else if (bid < 8448) {
        int l = bid - 8192;
        transp_body(a256_w1, awup, H, 256, H, nullptr, l & 7, l >> 3);
    } else if (bid < 8960) {
        int l = bid - 8448;
        transp_body(a512_w1, awup + (size_t)256 * H, H, 512, H, nullptr, l & 15, l >> 4);
    } else if (bid < 9216) {
        int l = bid - 8960;
        transp_body(a256_w2, awdT, 256, H, 768, nullptr, l & 31, l >> 5);
    } else if (bid < 9728) {
        int l = bid - 9216;
        transp_body(a512_w2, awdT + 256, 512, H, 768, nullptr, l & 31, l >> 5);
    } else if (bid < 9731) {
        int n = (bid - 9728) * 256 + threadIdx.x;
        if (n < 768) ab1[n] = (n < 256) ? a256_b1[n] : a512_b1[n - 256];
    } else if (bid < 9739) {
        int n = (bid - 9731) * 256 + threadIdx.x;   // 0..2047
        b2sel[n] = (n < 1024) ? a256_b2[n] : a512_b2[n - 1024];
    } else if (bid < 9803) {
        int l = bid - 9739;
        c01_partial_body(W2, ln_h_g, ln_h_b, pc0, pc1, H, l >> 2, l & 3);
    } else {
        ln1024_body(x, xn, ln_in_g, ln_in_b, bid - 9803);
    }
}

// ---------------------------------------------------------------------------
// Kernel 2: big1 — GEMM1 (h = gelu(xn@W1+b1) + row stats partials, 2048 blk)
// || masked adapter-up (tt, 384 blk).
// ---------------------------------------------------------------------------
__global__ __launch_bounds__(256) void big1(
    const unsigned short* __restrict__ xn, const unsigned short* __restrict__ W1T,
    const float* __restrict__ b1, unsigned short* __restrict__ h,
    float* __restrict__ ps, float* __restrict__ pq,
    const unsigned short* __restrict__ awup, const float* __restrict__ ab1,
    unsigned short* __restrict__ tt, const int* __restrict__ widx) {
    __shared__ __align__(16) unsigned short As[2][128 * 32];
    __shared__ __align__(16) unsigned short Bs[2][128 * 32];
    int bid = blockIdx.x;
    if (bid < 2048) {
        gemm_body<0>(As, Bs, bid, 32, 64, xn, 1024, W1T, 1024, b1, h,
                     nullptr, 4096, 1024, nullptr, nullptr, nullptr, nullptr,
                     nullptr, nullptr, ps, pq);
    } else {
        gemm_body<3>(As, Bs, bid - 2048, 6, 64, xn, 1024, awup, 1024, ab1, tt,
                     nullptr, 768, 1024, widx, nullptr, nullptr, nullptr,
                     nullptr, nullptr, nullptr, nullptr);
    }
}

// ---------------------------------------------------------------------------
// Kernel 3: mid_k — merged adapter-down GEMM (512 blk) || stats finalize
// (32 blk: rs, rs*mu from ps/pq partials) || c01 reduce (4 blk).
// ---------------------------------------------------------------------------
__global__ __launch_bounds__(256) void mid_k(
    const unsigned short* __restrict__ tt, const unsigned short* __restrict__ awdT,
    const float* __restrict__ b2sel, unsigned short* __restrict__ adp,
    const int* __restrict__ widx,
    const float* __restrict__ ps, const float* __restrict__ pq,
    float* __restrict__ stats,
    const float* __restrict__ pc0, const float* __restrict__ pc1,
    const float* __restrict__ b2, float* __restrict__ c0b2,
    float* __restrict__ c1) {
    __shared__ __align__(16) unsigned short As[2][128 * 32];
    __shared__ __align__(16) unsigned short Bs[2][128 * 32];
    int bid = blockIdx.x;
    if (bid < 512) {
        gemm_body<4>(As, Bs, bid, 8, 64, tt, 768, awdT, 768, b2sel, adp,
                     nullptr, 1024, 768, widx, nullptr, nullptr, nullptr,
                     nullptr, nullptr, nullptr, nullptr);
    } else if (bid < 544) {
        int row = (bid - 512) * 256 + threadIdx.x;   // 0..8191
        float s0 = 0.f, s1 = 0.f;
        const float* pr = ps + (size_t)row * 64;
        const float* qr = pq + (size_t)row * 64;
#pragma unroll
        for (int c = 0; c < 64; ++c) { s0 += pr[c]; s1 += qr[c]; }
        const float inv = 1.0f / 4096.0f;
        float mu = s0 * inv;
        float var = s1 * inv - mu * mu;
        float rs = rsqrtf(var + 1e-5f);
        stats[2 * (size_t)row]     = rs;
        stats[2 * (size_t)row + 1] = rs * mu;
    } else {
        int n = ((bid - 544) << 8) + threadIdx.x;    // 0..1023
        float s0 = b2[n], s1 = 0.f;
#pragma unroll
        for (int kc = 0; kc < 16; ++kc) {
            s0 += pc0[kc * 1024 + n];
            s1 += pc1[kc * 1024 + n];
        }
        c0b2[n] = s0;
        c1[n] = s1;
    }
}

// ---------------------------------------------------------------------------
// Kernel 4: final GEMM (2D grid, EPI 2).
// ---------------------------------------------------------------------------
__global__ __launch_bounds__(256) void gemm_fin(
    const unsigned short* __restrict__ A, int lda,
    const unsigned short* __restrict__ BT, int ldb,
    const float* __restrict__ bias, float* __restrict__ Cf, int N, int K,
    const int* __restrict__ idx, const float* __restrict__ wm,
    const unsigned short* __restrict__ adaptive,
    const unsigned short* __restrict__ xn,
    const float* __restrict__ c1v, const float* __restrict__ rstat) {
    __shared__ __align__(16) unsigned short As[2][128 * 32];
    __shared__ __align__(16) unsigned short Bs[2][128 * 32];
    gemm_body<2>(As, Bs, blockIdx.y * gridDim.x + blockIdx.x,
                 gridDim.x, gridDim.y, A, lda, BT, ldb, bias, nullptr, Cf, N, K,
                 idx, wm, adaptive, xn, c1v, rstat, nullptr, nullptr);
}

// ---------------------------------------------------------------------------
extern "C" void kernel_launch(void* const* d_in, const int* in_sizes, int n_in,
                              void* d_out, int out_size, void* d_ws, size_t ws_size,
                              hipStream_t stream) {
    const float* x       = (const float*)d_in[0];
    const float* wm      = (const float*)d_in[1];
    const int*   widx    = (const int*)d_in[2];
    const float* ln_in_g = (const float*)d_in[3];
    const float* ln_in_b = (const float*)d_in[4];
    const float* W1      = (const float*)d_in[5];
    const float* b1      = (const float*)d_in[6];
    const float* ln_h_g  = (const float*)d_in[7];
    const float* ln_h_b  = (const float*)d_in[8];
    const float* W2      = (const float*)d_in[9];
    const float* b2      = (const float*)d_in[10];
    const float* a256_w1 = (const float*)d_in[11];
    const float* a256_b1 = (const float*)d_in[12];
    const float* a256_w2 = (const float*)d_in[13];
    const float* a256_b2 = (const float*)d_in[14];
    const float* a512_w1 = (const float*)d_in[15];
    const float* a512_b1 = (const float*)d_in[16];
    const float* a512_w2 = (const float*)d_in[17];
    const float* a512_b2 = (const float*)d_in[18];
    float* out = (float*)d_out;

    const int T = 8192, H = 1024, F = 4096;

    unsigned short* ws0   = (unsigned short*)d_ws;
    unsigned short* xn    = ws0;                       // T*H      bf16
    unsigned short* h     = xn    + (size_t)T * H;     // T*F      bf16
    unsigned short* tt    = h     + (size_t)T * F;     // T*768    bf16 (masked)
    unsigned short* adp   = tt    + (size_t)T * 768;   // T*H      bf16
    unsigned short* W1T   = adp   + (size_t)T * H;     // F*H      bf16
    unsigned short* W2T   = W1T   + (size_t)H * F;     // H*F      bf16 (pre-scaled by ln_h_g)
    unsigned short* awup  = W2T   + (size_t)F * H;     // 768*1024 bf16
    unsigned short* awdT  = awup  + (size_t)768 * H;   // 1024*768 bf16 ([a256w2;a512w2]^T)
    float*          ab1   = (float*)(awdT + (size_t)H * 768);   // 768 fp32
    float*          b2sel = ab1 + 768;                 // 2048 fp32
    float*          stats = b2sel + 2048;              // T*2 fp32: rs, rs*mu
    float*          c0b2  = stats + (size_t)T * 2;     // H fp32
    float*          c1    = c0b2 + H;                  // H fp32
    float*          pc0   = c1 + H;                    // 16*1024 fp32 partials
    float*          pc1   = pc0 + 16 * 1024;           // 16*1024 fp32 partials
    float*          ps    = pc1 + 16 * 1024;           // T*64 fp32 row-sum partials
    float*          pq    = ps + (size_t)T * 64;       // T*64 fp32 row-sumsq partials

    // 1) all prep (6 transposes, bias tables, c01 partials, input LN)
    mega_prep<<<9803 + T, 256, 0, stream>>>(
        W1, W2, ln_h_g, ln_h_b, a256_w1, a512_w1, a256_w2, a512_w2,
        a256_b1, a512_b1, a256_b2, a512_b2, x, ln_in_g, ln_in_b,
        W1T, W2T, awup, awdT, ab1, b2sel, pc0, pc1, xn);

    // 2) GEMM1 (+row-stats partials) || masked adapter-up
    big1<<<2048 + 384, 256, 0, stream>>>(
        xn, W1T, b1, h, ps, pq, awup, ab1, tt, widx);

    // 3) merged adapter-down || stats finalize || c01 reduce
    mid_k<<<512 + 32 + 4, 256, 0, stream>>>(
        tt, awdT, b2sel, adp, widx, ps, pq, stats, pc0, pc1, b2, c0b2, c1);

    // 4) out = (rs*(h @ g.W2) + (b.W2 + b2) - rs*mu*c1) * wm + adaptive*(1-wm)
    gemm_fin<<<dim3(H / 128, T / 128), 256, 0, stream>>>(
        h, F, W2T, F, c0b2, out, H, F, widx, wm, adp, xn, c1, stats);
}

// Round 10
// 414.798 us; speedup vs baseline: 1.0710x; 1.0710x over previous
//
#include <hip/hip_runtime.h>
#include <cstdint>
#include <cstddef>

typedef unsigned short u16x8 __attribute__((ext_vector_type(8)));
typedef unsigned short u16x4 __attribute__((ext_vector_type(4)));
typedef __bf16 bf16x8 __attribute__((ext_vector_type(8)));
typedef float f32x4 __attribute__((ext_vector_type(4)));

__device__ __forceinline__ float b2f(unsigned short u) {
    union { unsigned int i; float f; } v;
    v.i = ((unsigned int)u) << 16;
    return v.f;
}

__device__ __forceinline__ unsigned short f2b(float f) {
    union { float f; unsigned int i; } v;
    v.f = f;
    unsigned int x = v.i;
    unsigned int lsb = (x >> 16) & 1u;
    x += 0x7FFFu + lsb;           // round-to-nearest-even
    return (unsigned short)(x >> 16);
}

__device__ __forceinline__ float gelu_exact(float x) {
    return 0.5f * x * (1.0f + erff(x * 0.70710678118654752f));
}

// async 16B global -> LDS (DMA). lds base is wave-uniform; lane i lands at
// base + i*16 bytes. [m97: global_load_lds_dwordx4]
__device__ __forceinline__ void ld_lds16(const unsigned short* g, unsigned short* l) {
    __builtin_amdgcn_global_load_lds(
        (const __attribute__((address_space(1))) void*)g,
        (__attribute__((address_space(3))) void*)l, 16, 0, 0);
}

// ---------------------------------------------------------------------------
// Device bodies for the fused block-range kernels.
// ---------------------------------------------------------------------------

// Transpose + cast (+ optional per-input-row scale): in R x C fp32 ->
// out[c*ldout + r] = in[r][c] * scale[r]. One 32x32 tile per block.
__device__ __forceinline__ void transp_body(const float* __restrict__ in,
                                            unsigned short* __restrict__ out,
                                            int R, int C, int ldout,
                                            const float* __restrict__ scale,
                                            int bx, int by) {
    __shared__ float tile[32][33];
    const int tx = threadIdx.x & 31;
    const int ty = threadIdx.x >> 5;     // 0..7
    int x = bx * 32 + tx;
    int y0 = by * 32;
    for (int k = 0; k < 32; k += 8)
        tile[ty + k][tx] = in[(size_t)(y0 + ty + k) * C + x];
    __syncthreads();
    int ox = y0 + tx;                    // input row index
    int oy = bx * 32;
    float sc = scale ? scale[ox] : 1.0f;
    for (int k = 0; k < 32; k += 8)
        out[(size_t)(oy + ty + k) * ldout + ox] = f2b(tile[tx][ty + k] * sc);
}

// K-parallel partial of c0/c1 (16 k-chunks x 4 n-chunks, no atomics).
__device__ __forceinline__ void c01_partial_body(const float* __restrict__ W2,
                                                 const float* __restrict__ g,
                                                 const float* __restrict__ b,
                                                 float* __restrict__ pc0,
                                                 float* __restrict__ pc1,
                                                 int N, int kc, int nb) {
    int n = (nb << 8) + threadIdx.x;
    int k0 = kc << 8;
    float p0 = 0.f, p1 = 0.f;
    for (int k = k0; k < k0 + 256; ++k) {
        float w = W2[(size_t)k * N + n];
        p0 += b[k] * w;
        p1 += g[k] * w;
    }
    pc0[kc * 1024 + n] = p0;
    pc1[kc * 1024 + n] = p1;
}

// LayerNorm over 1024 fp32 cols -> bf16, fully vectorized. One row per block.
__device__ __forceinline__ void ln1024_body(const float* __restrict__ in,
                                            unsigned short* __restrict__ out,
                                            const float* __restrict__ g,
                                            const float* __restrict__ b,
                                            int row) {
    const int t = threadIdx.x;
    f32x4 v = ((const f32x4*)(in + (size_t)row * 1024))[t];
    float s = v[0] + v[1] + v[2] + v[3];
    float s2 = v[0] * v[0] + v[1] * v[1] + v[2] * v[2] + v[3] * v[3];
#pragma unroll
    for (int o = 32; o > 0; o >>= 1) {
        s  += __shfl_down(s, o, 64);
        s2 += __shfl_down(s2, o, 64);
    }
    __shared__ float red[8];
    int lane = t & 63, w = t >> 6;
    if (lane == 0) { red[w] = s; red[4 + w] = s2; }
    __syncthreads();
    if (t == 0) {
        red[0] = red[0] + red[1] + red[2] + red[3];
        red[4] = red[4] + red[5] + red[6] + red[7];
    }
    __syncthreads();
    const float inv_n = 1.0f / 1024.0f;
    float mu = red[0] * inv_n;
    float var = red[4] * inv_n - mu * mu;
    float rs = rsqrtf(var + 1e-5f);
    f32x4 gv = ((const f32x4*)g)[t];
    f32x4 bv = ((const f32x4*)b)[t];
    u16x4 ov;
#pragma unroll
    for (int r = 0; r < 4; ++r) ov[r] = f2b((v[r] - mu) * rs * gv[r] + bv[r]);
    ((u16x4*)(out + (size_t)row * 1024))[t] = ov;
}

// Per-row LN stats over 4096 bf16 cols: st[2r] = rs, st[2r+1] = rs*mu.
__device__ __forceinline__ void rowstats_body(const unsigned short* __restrict__ h,
                                              float* __restrict__ st, int row) {
    const int t = threadIdx.x;
    const u16x8* p = (const u16x8*)(h + (size_t)row * 4096);
    float s = 0.f, s2 = 0.f;
#pragma unroll
    for (int i = 0; i < 2; ++i) {
        u16x8 v = p[t + (i << 8)];
#pragma unroll
        for (int r = 0; r < 8; ++r) { float f = b2f(v[r]); s += f; s2 += f * f; }
    }
#pragma unroll
    for (int o = 32; o > 0; o >>= 1) {
        s  += __shfl_down(s, o, 64);
        s2 += __shfl_down(s2, o, 64);
    }
    __shared__ float red2[8];
    int lane = t & 63, w = t >> 6;
    if (lane == 0) { red2[w] = s; red2[4 + w] = s2; }
    __syncthreads();
    if (t == 0) {
        float ss = red2[0] + red2[1] + red2[2] + red2[3];
        float qq = red2[4] + red2[5] + red2[6] + red2[7];
        const float inv = 1.0f / 4096.0f;
        float mu = ss * inv;
        float var = qq * inv - mu * mu;
        float rs = rsqrtf(var + 1e-5f);
        st[2 * (size_t)row]     = rs;
        st[2 * (size_t)row + 1] = rs * mu;
    }
}

// ---------------------------------------------------------------------------
// 128x128x32 GEMM body (2-phase, double-buffered gload_lds, XOR swizzle,
// XCD-aware bijective flat-id swizzle). A,BT bf16; fp32 acc; 256 threads.
// EPI 0: bias + exact GELU -> bf16 Cb  (pure — no stats; keeps 72 VGPR)
// EPI 3: masked adapter-up: Cb = active ? gelu(acc+bias) : 0, where
//        active = (col<256 ? idx[row]==0 : idx[row]==1). N=768.
// EPI 4: merged adapter-down: Cb = acc + bias_sel[idx[row]][col]
//        (bias table = [a256_b2 ; a512_b2], 2x1024). Writes all rows.
// EPI 2: folded-LN epilogue:
//        Cf = (rs*acc + c0b2[col] - rsmu*c1[col]) * wm + adaptive_sel*(1-wm)
// ---------------------------------------------------------------------------
template <int EPI>
__device__ __forceinline__ void gemm_body(
    unsigned short (*As)[128 * 32], unsigned short (*Bs)[128 * 32],
    int fid, int nbx, int nby,
    const unsigned short* __restrict__ A, int lda,
    const unsigned short* __restrict__ BT, int ldb,
    const float* __restrict__ bias, unsigned short* __restrict__ Cb,
    float* __restrict__ Cf, int N, int K,
    const int* __restrict__ idx,
    const float* __restrict__ wm,
    const unsigned short* __restrict__ adaptive,
    const unsigned short* __restrict__ xn,
    const float* __restrict__ c1v,
    const float* __restrict__ rstat) {
    const int t = threadIdx.x;

    int id = fid;
    const int nwg = nbx * nby;
    if ((nwg & 7) == 0) {
        const int cpx = nwg >> 3;
        id = (id & 7) * cpx + (id >> 3);
    }
    const int bx = id % nbx;
    const int by = id / nbx;
    const int m0 = by * 128;
    const int n0 = bx * 128;

    const int lane = t & 63;
    const int wid = t >> 6;

    const int srow = lane >> 2;
    const int sch  = (lane & 3) ^ (srow & 3);
    const int scol = sch << 3;

    const int wr = (wid >> 1) << 6;
    const int wc = (wid & 1) << 6;
    const int ml = lane & 15;
    const int q = lane >> 4;
    const int qsw = ((q ^ (ml & 3)) << 3);

    f32x4 acc[4][4];
#pragma unroll
    for (int i = 0; i < 4; ++i)
#pragma unroll
        for (int j = 0; j < 4; ++j)
#pragma unroll
            for (int r = 0; r < 4; ++r) acc[i][j][r] = 0.0f;

    const int nk = K >> 5;

#define STAGE(KT, BUF)                                                          \
    {                                                                           \
        _Pragma("unroll")                                                       \
        for (int hh = 0; hh < 2; ++hh) {                                        \
            int rbase = wid * 32 + hh * 16;                                     \
            int row = rbase + srow;                                             \
            ld_lds16(A  + (size_t)(m0 + row) * lda + (KT) * 32 + scol,          \
                     &As[BUF][rbase * 32]);                                     \
            ld_lds16(BT + (size_t)(n0 + row) * ldb + (KT) * 32 + scol,          \
                     &Bs[BUF][rbase * 32]);                                     \
        }                                                                       \
    }

    STAGE(0, 0);
    for (int kt = 0; kt < nk; ++kt) {
        const int cur = kt & 1;
        __syncthreads();
        if (kt + 1 < nk) STAGE(kt + 1, cur ^ 1);

        bf16x8 af[4], bf[4];
#pragma unroll
        for (int i = 0; i < 4; ++i)
            af[i] = *(const bf16x8*)(&As[cur][(wr + i * 16 + ml) * 32 + qsw]);
#pragma unroll
        for (int j = 0; j < 4; ++j)
            bf[j] = *(const bf16x8*)(&Bs[cur][(wc + j * 16 + ml) * 32 + qsw]);
#pragma unroll
        for (int i = 0; i < 4; ++i)
#pragma unroll
            for (int j = 0; j < 4; ++j)
                acc[i][j] = __builtin_amdgcn_mfma_f32_16x16x32_bf16(af[i], bf[j], acc[i][j], 0, 0, 0);
    }
#undef STAGE

    // C/D layout: col = lane&15, row = quad*4 + reg  [m89/m91-verified]
#pragma unroll
    for (int i = 0; i < 4; ++i) {
        float rsv[4], rmv[4], wv[4];
        int idv[4];
        if (EPI != 0) {
#pragma unroll
            for (int r = 0; r < 4; ++r) {
                int row = m0 + wr + i * 16 + q * 4 + r;
                idv[r] = idx[row];
                if (EPI == 2) {
                    wv[r] = wm[row];
                    rsv[r] = rstat[2 * (size_t)row];
                    rmv[r] = rstat[2 * (size_t)row + 1];
                }
            }
        }
#pragma unroll
        for (int j = 0; j < 4; ++j) {
            int col = n0 + wc + j * 16 + ml;
            float bv = bias[col];
            float bv1 = (EPI == 4) ? bias[1024 + col] : 0.0f;
            float c1c = (EPI == 2) ? c1v[col] : 0.0f;
#pragma unroll
            for (int r = 0; r < 4; ++r) {
                int row = m0 + wr + i * 16 + q * 4 + r;
                size_t off = (size_t)row * N + col;
                if (EPI == 0) {
                    Cb[off] = f2b(gelu_exact(acc[i][j][r] + bv));
                } else if (EPI == 3) {
                    bool act = (col < 256) ? (idv[r] == 0) : (idv[r] == 1);
                    Cb[off] = f2b(act ? gelu_exact(acc[i][j][r] + bv) : 0.0f);
                } else if (EPI == 4) {
                    float bsel = (idv[r] == 1) ? bv1 : bv;
                    Cb[off] = f2b(acc[i][j][r] + bsel);
                } else {
                    float bval = rsv[r] * acc[i][j][r] + bv - rmv[r] * c1c;
                    float a = b2f((idv[r] <= 1) ? adaptive[off] : xn[off]);
                    Cf[off] = bval * wv[r] + a * (1.0f - wv[r]);
                }
            }
        }
    }
}

// ---------------------------------------------------------------------------
// Kernel 1: mega_prep — all weight prep + input LN, block-range dispatched.
// [0,4096) W1T | [4096,8192) W2T*g | [8192,8448) a256w1T->awup |
// [8448,8960) a512w1T->awup+256K | [8960,9216) a256w2T->awdT (ld 768) |
// [9216,9728) a512w2T->awdT+256 (ld 768) | [9728,9731) ab1 concat |
// [9731,9739) b2sel table | [9739,9803) c01 partials | [9803,+8192) ln1024.
// ---------------------------------------------------------------------------
__global__ __launch_bounds__(256) void mega_prep(
    const float* __restrict__ W1, const float* __restrict__ W2,
    const float* __restrict__ ln_h_g, const float* __restrict__ ln_h_b,
    const float* __restrict__ a256_w1, const float* __restrict__ a512_w1,
    const float* __restrict__ a256_w2, const float* __restrict__ a512_w2,
    const float* __restrict__ a256_b1, const float* __restrict__ a512_b1,
    const float* __restrict__ a256_b2, const float* __restrict__ a512_b2,
    const float* __restrict__ x, const float* __restrict__ ln_in_g,
    const float* __restrict__ ln_in_b,
    unsigned short* __restrict__ W1T, unsigned short* __restrict__ W2T,
    unsigned short* __restrict__ awup, unsigned short* __restrict__ awdT,
    float* __restrict__ ab1, float* __restrict__ b2sel,
    float* __restrict__ pc0, float* __restrict__ pc1,
    unsigned short* __restrict__ xn) {
    const int H = 1024, F = 4096;
    int bid = blockIdx.x;
    if (bid < 4096) {
        transp_body(W1, W1T, H, F, H, nullptr, bid & 127, bid >> 7);
    } else if (bid < 8192) {
        int l = bid - 4096;
        transp_body(W2, W2T, F, H, F, ln_h_g, l & 31, l >> 5);
    } else if (bid < 8448) {
        int l = bid - 8192;
        transp_body(a256_w1, awup, H, 256, H, nullptr, l & 7, l >> 3);
    } else if (bid < 8960) {
        int l = bid - 8448;
        transp_body(a512_w1, awup + (size_t)256 * H, H, 512, H, nullptr, l & 15, l >> 4);
    } else if (bid < 9216) {
        int l = bid - 8960;
        transp_body(a256_w2, awdT, 256, H, 768, nullptr, l & 31, l >> 5);
    } else if (bid < 9728) {
        int l = bid - 9216;
        transp_body(a512_w2, awdT + 256, 512, H, 768, nullptr, l & 31, l >> 5);
    } else if (bid < 9731) {
        int n = (bid - 9728) * 256 + threadIdx.x;
        if (n < 768) ab1[n] = (n < 256) ? a256_b1[n] : a512_b1[n - 256];
    } else if (bid < 9739) {
        int n = (bid - 9731) * 256 + threadIdx.x;   // 0..2047
        b2sel[n] = (n < 1024) ? a256_b2[n] : a512_b2[n - 1024];
    } else if (bid < 9803) {
        int l = bid - 9739;
        c01_partial_body(W2, ln_h_g, ln_h_b, pc0, pc1, H, l >> 2, l & 3);
    } else {
        ln1024_body(x, xn, ln_in_g, ln_in_b, bid - 9803);
    }
}

// ---------------------------------------------------------------------------
// Kernel 2: GEMM1 standalone (pure EPI 0, 2D grid) — proven 72-VGPR config.
// ---------------------------------------------------------------------------
__global__ __launch_bounds__(256) void gemm1(
    const unsigned short* __restrict__ xn, const unsigned short* __restrict__ W1T,
    const float* __restrict__ b1, unsigned short* __restrict__ h) {
    __shared__ __align__(16) unsigned short As[2][128 * 32];
    __shared__ __align__(16) unsigned short Bs[2][128 * 32];
    gemm_body<0>(As, Bs, blockIdx.y * gridDim.x + blockIdx.x,
                 gridDim.x, gridDim.y, xn, 1024, W1T, 1024, b1, h,
                 nullptr, 4096, 1024, nullptr, nullptr, nullptr, nullptr,
                 nullptr, nullptr);
}

// ---------------------------------------------------------------------------
// Kernel 3: masked adapter-up GEMM (384 blk) || rowstats of h (8192 blk).
// ---------------------------------------------------------------------------
__global__ __launch_bounds__(256) void up_stats(
    const unsigned short* __restrict__ xn, const unsigned short* __restrict__ awup,
    const float* __restrict__ ab1, unsigned short* __restrict__ tt,
    const int* __restrict__ widx,
    const unsigned short* __restrict__ h, float* __restrict__ st) {
    __shared__ __align__(16) unsigned short As[2][128 * 32];
    __shared__ __align__(16) unsigned short Bs[2][128 * 32];
    int bid = blockIdx.x;
    if (bid < 384) {
        gemm_body<3>(As, Bs, bid, 6, 64, xn, 1024, awup, 1024, ab1, tt,
                     nullptr, 768, 1024, widx, nullptr, nullptr, nullptr,
                     nullptr, nullptr);
    } else {
        rowstats_body(h, st, bid - 384);
    }
}

// ---------------------------------------------------------------------------
// Kernel 4: merged adapter-down GEMM (512 blk, EPI 4) || c01 reduce (4 blk).
// ---------------------------------------------------------------------------
__global__ __launch_bounds__(256) void mid_k(
    const unsigned short* __restrict__ tt, const unsigned short* __restrict__ awdT,
    const float* __restrict__ b2sel, unsigned short* __restrict__ adp,
    const int* __restrict__ widx,
    const float* __restrict__ pc0, const float* __restrict__ pc1,
    const float* __restrict__ b2, float* __restrict__ c0b2,
    float* __restrict__ c1) {
    __shared__ __align__(16) unsigned short As[2][128 * 32];
    __shared__ __align__(16) unsigned short Bs[2][128 * 32];
    int bid = blockIdx.x;
    if (bid < 512) {
        gemm_body<4>(As, Bs, bid, 8, 64, tt, 768, awdT, 768, b2sel, adp,
                     nullptr, 1024, 768, widx, nullptr, nullptr, nullptr,
                     nullptr, nullptr);
    } else {
        int n = ((bid - 512) << 8) + threadIdx.x;    // 0..1023
        float s0 = b2[n], s1 = 0.f;
#pragma unroll
        for (int kc = 0; kc < 16; ++kc) {
            s0 += pc0[kc * 1024 + n];
            s1 += pc1[kc * 1024 + n];
        }
        c0b2[n] = s0;
        c1[n] = s1;
    }
}

// ---------------------------------------------------------------------------
// Kernel 5: final GEMM (2D grid, EPI 2).
// ---------------------------------------------------------------------------
__global__ __launch_bounds__(256) void gemm_fin(
    const unsigned short* __restrict__ A, int lda,
    const unsigned short* __restrict__ BT, int ldb,
    const float* __restrict__ bias, float* __restrict__ Cf, int N, int K,
    const int* __restrict__ idx, const float* __restrict__ wm,
    const unsigned short* __restrict__ adaptive,
    const unsigned short* __restrict__ xn,
    const float* __restrict__ c1v, const float* __restrict__ rstat) {
    __shared__ __align__(16) unsigned short As[2][128 * 32];
    __shared__ __align__(16) unsigned short Bs[2][128 * 32];
    gemm_body<2>(As, Bs, blockIdx.y * gridDim.x + blockIdx.x,
                 gridDim.x, gridDim.y, A, lda, BT, ldb, bias, nullptr, Cf, N, K,
                 idx, wm, adaptive, xn, c1v, rstat);
}

// ---------------------------------------------------------------------------
extern "C" void kernel_launch(void* const* d_in, const int* in_sizes, int n_in,
                              void* d_out, int out_size, void* d_ws, size_t ws_size,
                              hipStream_t stream) {
    const float* x       = (const float*)d_in[0];
    const float* wm      = (const float*)d_in[1];
    const int*   widx    = (const int*)d_in[2];
    const float* ln_in_g = (const float*)d_in[3];
    const float* ln_in_b = (const float*)d_in[4];
    const float* W1      = (const float*)d_in[5];
    const float* b1      = (const float*)d_in[6];
    const float* ln_h_g  = (const float*)d_in[7];
    const float* ln_h_b  = (const float*)d_in[8];
    const float* W2      = (const float*)d_in[9];
    const float* b2      = (const float*)d_in[10];
    const float* a256_w1 = (const float*)d_in[11];
    const float* a256_b1 = (const float*)d_in[12];
    const float* a256_w2 = (const float*)d_in[13];
    const float* a256_b2 = (const float*)d_in[14];
    const float* a512_w1 = (const float*)d_in[15];
    const float* a512_b1 = (const float*)d_in[16];
    const float* a512_w2 = (const float*)d_in[17];
    const float* a512_b2 = (const float*)d_in[18];
    float* out = (float*)d_out;

    const int T = 8192, H = 1024, F = 4096;

    unsigned short* ws0   = (unsigned short*)d_ws;
    unsigned short* xn    = ws0;                       // T*H      bf16
    unsigned short* h     = xn    + (size_t)T * H;     // T*F      bf16
    unsigned short* tt    = h     + (size_t)T * F;     // T*768    bf16 (masked)
    unsigned short* adp   = tt    + (size_t)T * 768;   // T*H      bf16
    unsigned short* W1T   = adp   + (size_t)T * H;     // F*H      bf16
    unsigned short* W2T   = W1T   + (size_t)H * F;     // H*F      bf16 (pre-scaled by ln_h_g)
    unsigned short* awup  = W2T   + (size_t)F * H;     // 768*1024 bf16
    unsigned short* awdT  = awup  + (size_t)768 * H;   // 1024*768 bf16 ([a256w2;a512w2]^T)
    float*          ab1   = (float*)(awdT + (size_t)H * 768);   // 768 fp32
    float*          b2sel = ab1 + 768;                 // 2048 fp32
    float*          stats = b2sel + 2048;              // T*2 fp32: rs, rs*mu
    float*          c0b2  = stats + (size_t)T * 2;     // H fp32
    float*          c1    = c0b2 + H;                  // H fp32
    float*          pc0   = c1 + H;                    // 16*1024 fp32 partials
    float*          pc1   = pc0 + 16 * 1024;           // 16*1024 fp32 partials

    // 1) all prep (6 transposes, bias tables, c01 partials, input LN)
    mega_prep<<<9803 + T, 256, 0, stream>>>(
        W1, W2, ln_h_g, ln_h_b, a256_w1, a512_w1, a256_w2, a512_w2,
        a256_b1, a512_b1, a256_b2, a512_b2, x, ln_in_g, ln_in_b,
        W1T, W2T, awup, awdT, ab1, b2sel, pc0, pc1, xn);

    // 2) base FFN up: h = gelu(xn @ W1 + b1)   [standalone, 72-VGPR config]
    gemm1<<<dim3(F / 128, T / 128), 256, 0, stream>>>(xn, W1T, b1, h);

    // 3) masked adapter-up || LN stats of h
    up_stats<<<384 + T, 256, 0, stream>>>(xn, awup, ab1, tt, widx, h, stats);

    // 4) merged adapter-down || c01 reduce
    mid_k<<<512 + 4, 256, 0, stream>>>(tt, awdT, b2sel, adp, widx,
                                       pc0, pc1, b2, c0b2, c1);

    // 5) out = (rs*(h @ g.W2) + (b.W2 + b2) - rs*mu*c1) * wm + adaptive*(1-wm)
    gemm_fin<<<dim3(H / 128, T / 128), 256, 0, stream>>>(
        h, F, W2T, F, c0b2, out, H, F, widx, wm, adp, xn, c1, stats);
}